// Round 1
// baseline (872.289 us; speedup 1.0000x reference)
//
#include <hip/hip_runtime.h>

#define F_IN 512
#define HID  16
#define NCLS 7

// deg[i] = 1 (self loop); zero agg1 (HID floats per node, via float4)
__global__ void k_init(float* __restrict__ deg, float4* __restrict__ agg1_4, int n) {
    int i = blockIdx.x * blockDim.x + threadIdx.x;
    if (i < n) deg[i] = 1.0f;
    if (i < n * (HID / 4)) agg1_4[i] = float4{0.f, 0.f, 0.f, 0.f};
}

__global__ void k_count(const int* __restrict__ col, float* __restrict__ deg, int n_edges) {
    int e = blockIdx.x * blockDim.x + threadIdx.x;
    if (e < n_edges) atomicAdd(&deg[col[e]], 1.0f);
}

__global__ void k_rsqrt(float* __restrict__ deg, int n) {
    int i = blockIdx.x * blockDim.x + threadIdx.x;
    if (i < n) deg[i] = rsqrtf(deg[i]);  // deg >= 1 always
}

// h1 = x @ W1   (no bias). 1 thread per node; k unrolled by 32 so each lane
// consumes whole 128B lines despite the 2KB row stride. W1 accesses are
// wave-uniform -> scalar loads.
__global__ __launch_bounds__(256) void k_gemm1(const float* __restrict__ x,
                                               const float* __restrict__ W1,
                                               float* __restrict__ h1, int n) {
    int node = blockIdx.x * blockDim.x + threadIdx.x;
    if (node >= n) return;
    float acc[HID];
#pragma unroll
    for (int j = 0; j < HID; j++) acc[j] = 0.f;
    const float* xr = x + (size_t)node * F_IN;
    for (int k0 = 0; k0 < F_IN; k0 += 32) {
        float4 xv[8];
        const float4* xp = (const float4*)(xr + k0);
#pragma unroll
        for (int u = 0; u < 8; u++) xv[u] = xp[u];
#pragma unroll
        for (int u = 0; u < 8; u++) {
#pragma unroll
            for (int kk = 0; kk < 4; kk++) {
                float xk = ((const float*)&xv[u])[kk];
                const float* wr = W1 + (size_t)(k0 + u * 4 + kk) * HID;
#pragma unroll
                for (int j = 0; j < HID; j++) acc[j] = fmaf(xk, wr[j], acc[j]);
            }
        }
    }
    float4* o4 = (float4*)(h1 + (size_t)node * HID);
#pragma unroll
    for (int q = 0; q < 4; q++)
        o4[q] = float4{acc[q * 4 + 0], acc[q * 4 + 1], acc[q * 4 + 2], acc[q * 4 + 3]};
}

// agg1[col] += dinv[row]*dinv[col] * h1[row]  over edges; 16 threads/edge.
__global__ void k_scatter1(const int* __restrict__ ei, const float* __restrict__ dinv,
                           const float* __restrict__ h1, float* __restrict__ agg1,
                           int n_edges) {
    int g = blockIdx.x * blockDim.x + threadIdx.x;
    int e = g >> 4, j = g & 15;
    if (e >= n_edges) return;
    int r = ei[e], c = ei[n_edges + e];
    float norm = dinv[r] * dinv[c];
    atomicAdd(&agg1[(size_t)c * HID + j], norm * h1[(size_t)r * HID + j]);
}

// z = relu(agg1 + dinv^2*h1 + b1); t = z @ W2; out = dinv^2*t + b2 (self loop + bias)
__global__ void k_node2(const float* __restrict__ dinv, const float* __restrict__ h1,
                        const float* __restrict__ agg1, const float* __restrict__ b1,
                        const float* __restrict__ W2, const float* __restrict__ b2,
                        float* __restrict__ t, float* __restrict__ out, int n) {
    int i = blockIdx.x * blockDim.x + threadIdx.x;
    if (i >= n) return;
    float d2 = dinv[i];
    d2 *= d2;
    float z[HID];
    const float4* a4 = (const float4*)(agg1 + (size_t)i * HID);
    const float4* h4 = (const float4*)(h1 + (size_t)i * HID);
#pragma unroll
    for (int q = 0; q < 4; q++) {
        float4 av = a4[q], hv = h4[q];
        z[q * 4 + 0] = fmaxf(0.f, fmaf(d2, hv.x, av.x) + b1[q * 4 + 0]);
        z[q * 4 + 1] = fmaxf(0.f, fmaf(d2, hv.y, av.y) + b1[q * 4 + 1]);
        z[q * 4 + 2] = fmaxf(0.f, fmaf(d2, hv.z, av.z) + b1[q * 4 + 2]);
        z[q * 4 + 3] = fmaxf(0.f, fmaf(d2, hv.w, av.w) + b1[q * 4 + 3]);
    }
#pragma unroll
    for (int c = 0; c < NCLS; c++) {
        float s = 0.f;
#pragma unroll
        for (int j = 0; j < HID; j++) s = fmaf(z[j], W2[j * NCLS + c], s);
        t[(size_t)i * NCLS + c] = s;
        out[(size_t)i * NCLS + c] = fmaf(d2, s, b2[c]);
    }
}

// out[col] += norm * t[row] over edges; 8 threads/edge (1 idle lane of 8).
__global__ void k_scatter2(const int* __restrict__ ei, const float* __restrict__ dinv,
                           const float* __restrict__ t, float* __restrict__ out,
                           int n_edges) {
    int g = blockIdx.x * blockDim.x + threadIdx.x;
    int e = g >> 3, c = g & 7;
    if (e >= n_edges || c >= NCLS) return;
    int r = ei[e], cl = ei[n_edges + e];
    float norm = dinv[r] * dinv[cl];
    atomicAdd(&out[(size_t)cl * NCLS + c], norm * t[(size_t)r * NCLS + c]);
}

extern "C" void kernel_launch(void* const* d_in, const int* in_sizes, int n_in,
                              void* d_out, int out_size, void* d_ws, size_t ws_size,
                              hipStream_t stream) {
    const float* x  = (const float*)d_in[0];
    const int*   ei = (const int*)d_in[1];
    const float* W1 = (const float*)d_in[2];
    const float* b1 = (const float*)d_in[3];
    const float* W2 = (const float*)d_in[4];
    const float* b2 = (const float*)d_in[5];
    float* out = (float*)d_out;

    int n = in_sizes[0] / F_IN;   // 100000
    int E = in_sizes[1] / 2;      // 3200000

    float* ws   = (float*)d_ws;
    float* deg  = ws;                         // n floats (becomes dinv in-place)
    float* h1   = ws + n;                     // 16n
    float* agg1 = h1 + (size_t)16 * n;        // 16n
    float* t    = agg1 + (size_t)16 * n;      // 7n

    const int B = 256;
    k_init<<<dim3((n * 4 + B - 1) / B), dim3(B), 0, stream>>>(deg, (float4*)agg1, n);
    k_count<<<dim3((E + B - 1) / B), dim3(B), 0, stream>>>(ei + E, deg, E);
    k_rsqrt<<<dim3((n + B - 1) / B), dim3(B), 0, stream>>>(deg, n);
    k_gemm1<<<dim3((n + B - 1) / B), dim3(B), 0, stream>>>(x, W1, h1, n);
    k_scatter1<<<dim3((int)(((size_t)E * 16 + B - 1) / B)), dim3(B), 0, stream>>>(ei, deg, h1, agg1, E);
    k_node2<<<dim3((n + B - 1) / B), dim3(B), 0, stream>>>(deg, h1, agg1, b1, W2, b2, t, out, n);
    k_scatter2<<<dim3((int)(((size_t)E * 8 + B - 1) / B)), dim3(B), 0, stream>>>(ei, deg, t, out, E);
}

// Round 2
// 852.754 us; speedup vs baseline: 1.0229x; 1.0229x over previous
//
#include <hip/hip_runtime.h>

#define F_IN 512
#define HID  16
#define NCLS 7

// ---------------- CSR build ----------------

__global__ void k_zero_cnt(int* __restrict__ cnt, int n) {
    int i = blockIdx.x * blockDim.x + threadIdx.x;
    if (i < n) cnt[i] = 0;
}

__global__ void k_hist(const int* __restrict__ col, int* __restrict__ cnt, int E) {
    int e = blockIdx.x * blockDim.x + threadIdx.x;
    if (e < E) atomicAdd(&cnt[col[e]], 1);
}

__global__ void k_dinv(const int* __restrict__ cnt, float* __restrict__ dinv, int n) {
    int i = blockIdx.x * blockDim.x + threadIdx.x;
    if (i < n) dinv[i] = rsqrtf((float)(cnt[i] + 1));  // +1 self loop, deg >= 1
}

// block-level exclusive scan of cnt -> row_ptr (local), block sums -> bsums
__global__ void k_scanA(const int* __restrict__ cnt, int* __restrict__ row_ptr,
                        int* __restrict__ bsums, int n) {
    __shared__ int s[256];
    int tid = threadIdx.x;
    int i = blockIdx.x * 256 + tid;
    int v = (i < n) ? cnt[i] : 0;
    s[tid] = v;
    __syncthreads();
    for (int off = 1; off < 256; off <<= 1) {
        int t = 0;
        if (tid >= off) t = s[tid - off];
        __syncthreads();
        if (tid >= off) s[tid] += t;
        __syncthreads();
    }
    if (i < n) row_ptr[i] = s[tid] - v;  // exclusive within block
    if (tid == 255) bsums[blockIdx.x] = s[255];
}

// exclusive scan of nb (<512) block sums, in place
__global__ void k_scanB(int* __restrict__ bsums, int nb) {
    __shared__ int s[512];
    int tid = threadIdx.x;
    int v = (tid < nb) ? bsums[tid] : 0;
    s[tid] = v;
    __syncthreads();
    for (int off = 1; off < 512; off <<= 1) {
        int t = 0;
        if (tid >= off) t = s[tid - off];
        __syncthreads();
        if (tid >= off) s[tid] += t;
        __syncthreads();
    }
    if (tid < nb) bsums[tid] = s[tid] - v;
    __syncthreads();
}

// add block offsets; copy final row_ptr into cursor array; row_ptr[n] = E
__global__ void k_scanC(int* __restrict__ row_ptr, const int* __restrict__ bsums,
                        int* __restrict__ cur, int n, int E) {
    int i = blockIdx.x * blockDim.x + threadIdx.x;
    if (i < n) {
        int v = row_ptr[i] + bsums[blockIdx.x];
        row_ptr[i] = v;
        cur[i] = v;
    }
    if (i == 0) row_ptr[n] = E;
}

// place each edge's source node into its destination's CSR segment
__global__ void k_fill(const int* __restrict__ ei, int* __restrict__ cur,
                       int* __restrict__ srcarr, int E) {
    int e = blockIdx.x * blockDim.x + threadIdx.x;
    if (e >= E) return;
    int r = ei[e];
    int c = ei[E + e];
    int p = atomicAdd(&cur[c], 1);
    srcarr[p] = r;
}

// ---------------- layer math ----------------

// h1 = x @ W1. 1 thread/node; k unrolled by 32 so each lane consumes whole
// 128B lines; W1 accesses wave-uniform -> scalar loads.
__global__ __launch_bounds__(256) void k_gemm1(const float* __restrict__ x,
                                               const float* __restrict__ W1,
                                               float* __restrict__ h1, int n) {
    int node = blockIdx.x * blockDim.x + threadIdx.x;
    if (node >= n) return;
    float acc[HID];
#pragma unroll
    for (int j = 0; j < HID; j++) acc[j] = 0.f;
    const float* xr = x + (size_t)node * F_IN;
    for (int k0 = 0; k0 < F_IN; k0 += 32) {
        float4 xv[8];
        const float4* xp = (const float4*)(xr + k0);
#pragma unroll
        for (int u = 0; u < 8; u++) xv[u] = xp[u];
#pragma unroll
        for (int u = 0; u < 8; u++) {
#pragma unroll
            for (int kk = 0; kk < 4; kk++) {
                float xk = ((const float*)&xv[u])[kk];
                const float* wr = W1 + (size_t)(k0 + u * 4 + kk) * HID;
#pragma unroll
                for (int j = 0; j < HID; j++) acc[j] = fmaf(xk, wr[j], acc[j]);
            }
        }
    }
    float4* o4 = (float4*)(h1 + (size_t)node * HID);
#pragma unroll
    for (int q = 0; q < 4; q++)
        o4[q] = float4{acc[q * 4 + 0], acc[q * 4 + 1], acc[q * 4 + 2], acc[q * 4 + 3]};
}

// Gather layer 1 + fused relu + (z @ W2) -> t (stride 8, pad zeroed).
// 4 lanes per node; lane q owns h-features [4q, 4q+4).
__global__ __launch_bounds__(256) void k_gather1(
    const int* __restrict__ row_ptr, const int* __restrict__ srcarr,
    const float* __restrict__ dinv, const float* __restrict__ h1,
    const float* __restrict__ b1, const float* __restrict__ W2,
    float* __restrict__ t, int n) {
    int g = blockIdx.x * blockDim.x + threadIdx.x;
    int node = g >> 2, q = g & 3;
    if (node >= n) return;
    int eb = row_ptr[node], ee = row_ptr[node + 1];
    float dc = dinv[node];
    const float4* h4 = (const float4*)h1;
    float4 acc = {0.f, 0.f, 0.f, 0.f};
    for (int e = eb; e < ee; ++e) {
        int r = srcarr[e];
        float nm = dinv[r] * dc;
        float4 hv = h4[(size_t)r * 4 + q];
        acc.x = fmaf(nm, hv.x, acc.x);
        acc.y = fmaf(nm, hv.y, acc.y);
        acc.z = fmaf(nm, hv.z, acc.z);
        acc.w = fmaf(nm, hv.w, acc.w);
    }
    // self loop + bias + relu
    float4 hs = h4[(size_t)node * 4 + q];
    float d2 = dc * dc;
    float4 bq = ((const float4*)b1)[q];
    float4 z4;
    z4.x = fmaxf(fmaf(d2, hs.x, acc.x) + bq.x, 0.f);
    z4.y = fmaxf(fmaf(d2, hs.y, acc.y) + bq.y, 0.f);
    z4.z = fmaxf(fmaf(d2, hs.z, acc.z) + bq.z, 0.f);
    z4.w = fmaxf(fmaf(d2, hs.w, acc.w) + bq.w, 0.f);
    // collect all 16 z across the 4-lane group
    float z[HID];
#pragma unroll
    for (int qq = 0; qq < 4; qq++) {
        z[qq * 4 + 0] = __shfl(z4.x, qq, 4);
        z[qq * 4 + 1] = __shfl(z4.y, qq, 4);
        z[qq * 4 + 2] = __shfl(z4.z, qq, 4);
        z[qq * 4 + 3] = __shfl(z4.w, qq, 4);
    }
    // lane q computes t columns 2q and 2q+1 (col 7 = pad = 0)
    int j0 = q * 2, j1 = q * 2 + 1;
    float t0 = 0.f, t1 = 0.f;
#pragma unroll
    for (int k = 0; k < HID; k++) {
        t0 = fmaf(z[k], W2[k * NCLS + j0], t0);
        if (j1 < NCLS) t1 = fmaf(z[k], W2[k * NCLS + j1], t1);
    }
    if (j1 >= NCLS) t1 = 0.f;
    ((float2*)t)[(size_t)node * 4 + q] = float2{t0, t1};
}

// Gather layer 2: out[node] = sum_edges norm * t[src] + d2*t[node] + b2.
// 8 lanes per node (lane 7 reads pad, discarded). Writes every output elem.
__global__ __launch_bounds__(256) void k_gather2(
    const int* __restrict__ row_ptr, const int* __restrict__ srcarr,
    const float* __restrict__ dinv, const float* __restrict__ t,
    const float* __restrict__ b2, float* __restrict__ out, int n) {
    int g = blockIdx.x * blockDim.x + threadIdx.x;
    int node = g >> 3, j = g & 7;
    if (node >= n) return;
    int eb = row_ptr[node], ee = row_ptr[node + 1];
    float dc = dinv[node];
    float acc = 0.f;
    for (int e = eb; e < ee; ++e) {
        int r = srcarr[e];
        float nm = dinv[r] * dc;
        acc = fmaf(nm, t[(size_t)r * 8 + j], acc);
    }
    acc = fmaf(dc * dc, t[(size_t)node * 8 + j], acc);
    if (j < NCLS) out[(size_t)node * NCLS + j] = acc + b2[j];
}

extern "C" void kernel_launch(void* const* d_in, const int* in_sizes, int n_in,
                              void* d_out, int out_size, void* d_ws, size_t ws_size,
                              hipStream_t stream) {
    const float* x  = (const float*)d_in[0];
    const int*   ei = (const int*)d_in[1];
    const float* W1 = (const float*)d_in[2];
    const float* b1 = (const float*)d_in[3];
    const float* W2 = (const float*)d_in[4];
    const float* b2 = (const float*)d_in[5];
    float* out = (float*)d_out;

    int n = in_sizes[0] / F_IN;   // 100000
    int E = in_sizes[1] / 2;      // 3200000

    float* ws = (float*)d_ws;
    float* dinv    = ws;                                  // n
    float* h1      = ws + n;                              // 16n
    float* t       = ws + (size_t)17 * n;                 // 8n (stride-8 padded)
    // aliases inside t-region: all dead before gather1 writes t
    int*   cnt     = (int*)t;                             // n
    int*   cur     = (int*)t + n;                         // n
    int*   bsums   = (int*)t + 2 * (size_t)n;             // <=512
    int*   row_ptr = (int*)(ws + (size_t)25 * n);         // n+1
    int*   srcarr  = (int*)(ws + (size_t)25 * n) + n + 4; // E

    const int B = 256;
    int NB = (n + B - 1) / B;  // 391 (<512 required by k_scanB)

    k_zero_cnt<<<dim3(NB), dim3(B), 0, stream>>>(cnt, n);
    k_hist<<<dim3((E + B - 1) / B), dim3(B), 0, stream>>>(ei + E, cnt, E);
    k_dinv<<<dim3(NB), dim3(B), 0, stream>>>(cnt, dinv, n);
    k_scanA<<<dim3(NB), dim3(B), 0, stream>>>(cnt, row_ptr, bsums, n);
    k_scanB<<<dim3(1), dim3(512), 0, stream>>>(bsums, NB);
    k_scanC<<<dim3(NB), dim3(B), 0, stream>>>(row_ptr, bsums, cur, n, E);
    k_fill<<<dim3((E + B - 1) / B), dim3(B), 0, stream>>>(ei, cur, srcarr, E);
    k_gemm1<<<dim3(NB), dim3(B), 0, stream>>>(x, W1, h1, n);
    k_gather1<<<dim3((n * 4 + B - 1) / B), dim3(B), 0, stream>>>(row_ptr, srcarr, dinv, h1, b1, W2, t, n);
    k_gather2<<<dim3((n * 8 + B - 1) / B), dim3(B), 0, stream>>>(row_ptr, srcarr, dinv, t, b2, out, n);
}

// Round 3
// 616.889 us; speedup vs baseline: 1.4140x; 1.3823x over previous
//
#include <hip/hip_runtime.h>

#define F_IN 512
#define HID  16
#define NCLS 7
#define BSH  7            // log2(nodes per bucket)
#define NPB  128          // nodes per bucket
#define MAXBKT 1024       // supports n <= 131072
#define GRID_P 512        // blocks for hist/partition passes

// ---------------- bucketed CSR build ----------------

__global__ void k_zero(int* __restrict__ p, int m) {
    int i = blockIdx.x * blockDim.x + threadIdx.x;
    if (i < m) p[i] = 0;
}

// bucket histogram: LDS-aggregate, flush to line-padded global counters
__global__ void k_bhist(const int* __restrict__ dst, int* __restrict__ bcnt,
                        int E, int nbkt, int chunk) {
    __shared__ int h[MAXBKT];
    for (int i = threadIdx.x; i < nbkt; i += blockDim.x) h[i] = 0;
    __syncthreads();
    int base = blockIdx.x * chunk;
    int end = min(base + chunk, E);
    for (int e = base + threadIdx.x; e < end; e += blockDim.x)
        atomicAdd(&h[((unsigned)dst[e]) >> BSH], 1);
    __syncthreads();
    for (int i = threadIdx.x; i < nbkt; i += blockDim.x)
        if (h[i]) atomicAdd(&bcnt[i * 16], h[i]);   // stride-16: one counter per line
}

// exclusive scan of nbkt (<=1024) padded counts -> dense bptr + padded bcur
__global__ void k_bscan(const int* __restrict__ bcnt, int* __restrict__ bptr,
                        int* __restrict__ bcur, int nbkt) {
    __shared__ int s[1024];
    int tid = threadIdx.x;
    int v = (tid < nbkt) ? bcnt[tid * 16] : 0;
    s[tid] = v;
    __syncthreads();
    for (int off = 1; off < 1024; off <<= 1) {
        int t = (tid >= off) ? s[tid - off] : 0;
        __syncthreads();
        if (tid >= off) s[tid] += t;
        __syncthreads();
    }
    if (tid < nbkt) {
        int e = s[tid] - v;
        bptr[tid] = e;
        bcur[tid * 16] = e;
    }
}

// partition edges into bucket segments as packed (src<<BSH)|local_dst
__global__ void k_part(const int* __restrict__ ei, int* __restrict__ bcur,
                       unsigned* __restrict__ pairs, int E, int nbkt, int chunk) {
    __shared__ int h[MAXBKT];
    __shared__ int cur[MAXBKT];
    int tid = threadIdx.x;
    for (int i = tid; i < nbkt; i += blockDim.x) h[i] = 0;
    __syncthreads();
    int base = blockIdx.x * chunk;
    int end = min(base + chunk, E);
    for (int e = base + tid; e < end; e += blockDim.x)
        atomicAdd(&h[((unsigned)ei[E + e]) >> BSH], 1);
    __syncthreads();
    for (int i = tid; i < nbkt; i += blockDim.x) {
        int c = h[i];
        cur[i] = c ? atomicAdd(&bcur[i * 16], c) : 0;
    }
    __syncthreads();
    for (int e = base + tid; e < end; e += blockDim.x) {
        int d = ei[E + e];
        int b = ((unsigned)d) >> BSH;
        int pos = atomicAdd(&cur[b], 1);
        pairs[pos] = (((unsigned)ei[e]) << BSH) | (unsigned)(d & (NPB - 1));
    }
}

// per-bucket: LDS hist + scan -> row_ptr, dinv; LDS-cursor fill of srcarr
// (16KB destination window per block -> L2-resident, no write amplification)
__global__ __launch_bounds__(NPB) void k_bfill(
    const unsigned* __restrict__ pairs, const int* __restrict__ bptr,
    int* __restrict__ row_ptr, int* __restrict__ srcarr,
    float* __restrict__ dinv, int n, int E, int nbkt) {
    int b = blockIdx.x, tid = threadIdx.x;
    int pb = bptr[b];
    int pe = (b + 1 < nbkt) ? bptr[b + 1] : E;
    __shared__ int h[NPB];
    __shared__ int s[NPB];
    h[tid] = 0;
    __syncthreads();
    for (int p = pb + tid; p < pe; p += NPB)
        atomicAdd(&h[pairs[p] & (NPB - 1)], 1);
    __syncthreads();
    int cnt = h[tid];
    s[tid] = cnt;
    __syncthreads();
    for (int off = 1; off < NPB; off <<= 1) {
        int t = (tid >= off) ? s[tid - off] : 0;
        __syncthreads();
        if (tid >= off) s[tid] += t;
        __syncthreads();
    }
    int excl = s[tid] - cnt;
    int node = (b << BSH) + tid;
    if (node < n) {
        row_ptr[node] = pb + excl;
        dinv[node] = rsqrtf((float)(cnt + 1));  // +1 self loop
    }
    h[tid] = pb + excl;  // reuse as cursor
    __syncthreads();
    for (int p = pb + tid; p < pe; p += NPB) {
        unsigned v = pairs[p];
        int pos = atomicAdd(&h[v & (NPB - 1)], 1);
        srcarr[pos] = (int)(v >> BSH);
    }
    if (b == 0 && tid == 0) row_ptr[n] = E;
}

// ---------------- layer math ----------------

// h1 = x @ W1. 1 thread/node; k unrolled by 32 so each lane consumes whole
// 128B lines; W1 accesses wave-uniform -> scalar loads.
__global__ __launch_bounds__(256) void k_gemm1(const float* __restrict__ x,
                                               const float* __restrict__ W1,
                                               float* __restrict__ h1, int n) {
    int node = blockIdx.x * blockDim.x + threadIdx.x;
    if (node >= n) return;
    float acc[HID];
#pragma unroll
    for (int j = 0; j < HID; j++) acc[j] = 0.f;
    const float* xr = x + (size_t)node * F_IN;
    for (int k0 = 0; k0 < F_IN; k0 += 32) {
        float4 xv[8];
        const float4* xp = (const float4*)(xr + k0);
#pragma unroll
        for (int u = 0; u < 8; u++) xv[u] = xp[u];
#pragma unroll
        for (int u = 0; u < 8; u++) {
#pragma unroll
            for (int kk = 0; kk < 4; kk++) {
                float xk = ((const float*)&xv[u])[kk];
                const float* wr = W1 + (size_t)(k0 + u * 4 + kk) * HID;
#pragma unroll
                for (int j = 0; j < HID; j++) acc[j] = fmaf(xk, wr[j], acc[j]);
            }
        }
    }
    float4* o4 = (float4*)(h1 + (size_t)node * HID);
#pragma unroll
    for (int q = 0; q < 4; q++)
        o4[q] = float4{acc[q * 4 + 0], acc[q * 4 + 1], acc[q * 4 + 2], acc[q * 4 + 3]};
}

// Gather layer 1 + fused relu + (z @ W2) -> t (stride 8, pad zeroed).
// 4 lanes per node; lane q owns h-features [4q, 4q+4).
__global__ __launch_bounds__(256) void k_gather1(
    const int* __restrict__ row_ptr, const int* __restrict__ srcarr,
    const float* __restrict__ dinv, const float* __restrict__ h1,
    const float* __restrict__ b1, const float* __restrict__ W2,
    float* __restrict__ t, int n) {
    int g = blockIdx.x * blockDim.x + threadIdx.x;
    int node = g >> 2, q = g & 3;
    if (node >= n) return;
    int eb = row_ptr[node], ee = row_ptr[node + 1];
    float dc = dinv[node];
    const float4* h4 = (const float4*)h1;
    float4 acc = {0.f, 0.f, 0.f, 0.f};
    for (int e = eb; e < ee; ++e) {
        int r = srcarr[e];
        float nm = dinv[r] * dc;
        float4 hv = h4[(size_t)r * 4 + q];
        acc.x = fmaf(nm, hv.x, acc.x);
        acc.y = fmaf(nm, hv.y, acc.y);
        acc.z = fmaf(nm, hv.z, acc.z);
        acc.w = fmaf(nm, hv.w, acc.w);
    }
    float4 hs = h4[(size_t)node * 4 + q];
    float d2 = dc * dc;
    float4 bq = ((const float4*)b1)[q];
    float4 z4;
    z4.x = fmaxf(fmaf(d2, hs.x, acc.x) + bq.x, 0.f);
    z4.y = fmaxf(fmaf(d2, hs.y, acc.y) + bq.y, 0.f);
    z4.z = fmaxf(fmaf(d2, hs.z, acc.z) + bq.z, 0.f);
    z4.w = fmaxf(fmaf(d2, hs.w, acc.w) + bq.w, 0.f);
    float z[HID];
#pragma unroll
    for (int qq = 0; qq < 4; qq++) {
        z[qq * 4 + 0] = __shfl(z4.x, qq, 4);
        z[qq * 4 + 1] = __shfl(z4.y, qq, 4);
        z[qq * 4 + 2] = __shfl(z4.z, qq, 4);
        z[qq * 4 + 3] = __shfl(z4.w, qq, 4);
    }
    int j0 = q * 2, j1 = q * 2 + 1;
    float t0 = 0.f, t1 = 0.f;
#pragma unroll
    for (int k = 0; k < HID; k++) {
        t0 = fmaf(z[k], W2[k * NCLS + j0], t0);
        if (j1 < NCLS) t1 = fmaf(z[k], W2[k * NCLS + j1], t1);
    }
    if (j1 >= NCLS) t1 = 0.f;
    ((float2*)t)[(size_t)node * 4 + q] = float2{t0, t1};
}

// Gather layer 2: out[node] = sum_edges norm * t[src] + d2*t[node] + b2.
__global__ __launch_bounds__(256) void k_gather2(
    const int* __restrict__ row_ptr, const int* __restrict__ srcarr,
    const float* __restrict__ dinv, const float* __restrict__ t,
    const float* __restrict__ b2, float* __restrict__ out, int n) {
    int g = blockIdx.x * blockDim.x + threadIdx.x;
    int node = g >> 3, j = g & 7;
    if (node >= n) return;
    int eb = row_ptr[node], ee = row_ptr[node + 1];
    float dc = dinv[node];
    float acc = 0.f;
    for (int e = eb; e < ee; ++e) {
        int r = srcarr[e];
        float nm = dinv[r] * dc;
        acc = fmaf(nm, t[(size_t)r * 8 + j], acc);
    }
    acc = fmaf(dc * dc, t[(size_t)node * 8 + j], acc);
    if (j < NCLS) out[(size_t)node * NCLS + j] = acc + b2[j];
}

extern "C" void kernel_launch(void* const* d_in, const int* in_sizes, int n_in,
                              void* d_out, int out_size, void* d_ws, size_t ws_size,
                              hipStream_t stream) {
    const float* x  = (const float*)d_in[0];
    const int*   ei = (const int*)d_in[1];
    const float* b1 = (const float*)d_in[3];
    const float* W1 = (const float*)d_in[2];
    const float* W2 = (const float*)d_in[4];
    const float* b2 = (const float*)d_in[5];
    float* out = (float*)d_out;

    int n = in_sizes[0] / F_IN;   // 100000
    int E = in_sizes[1] / 2;      // 3200000
    int nbkt = (n + NPB - 1) >> BSH;  // 782

    float* ws = (float*)d_ws;
    float* dinv    = ws;                                   // n
    int*   row_ptr = (int*)(ws + n);                       // n+1 (pad 4)
    int*   srcarr  = (int*)(ws + 2 * (size_t)n + 4);       // E
    float* R       = ws + 2 * (size_t)n + 4 + E;           // E floats region
    unsigned* pairs = (unsigned*)R;                        // E (dead after k_bfill)
    float* h1      = R;                                    // 16n (aliases pairs)
    float* t       = R + 16 * (size_t)n;                   // 8n  (aliases pairs)
    int*   bcnt    = (int*)(R + E);                        // 1024*16 (line-padded)
    int*   bptr    = bcnt + 1024 * 16;                     // 1024 dense
    int*   bcur    = bptr + 1024;                          // 1024*16 (line-padded)

    const int B = 256;
    int chunk = (E + GRID_P - 1) / GRID_P;

    k_zero<<<dim3((1024 * 16 + B - 1) / B), dim3(B), 0, stream>>>(bcnt, 1024 * 16);
    k_bhist<<<dim3(GRID_P), dim3(B), 0, stream>>>(ei + E, bcnt, E, nbkt, chunk);
    k_bscan<<<dim3(1), dim3(1024), 0, stream>>>(bcnt, bptr, bcur, nbkt);
    k_part<<<dim3(GRID_P), dim3(B), 0, stream>>>(ei, bcur, pairs, E, nbkt, chunk);
    k_bfill<<<dim3(nbkt), dim3(NPB), 0, stream>>>(pairs, bptr, row_ptr, srcarr, dinv, n, E, nbkt);
    k_gemm1<<<dim3((n + B - 1) / B), dim3(B), 0, stream>>>(x, W1, h1, n);
    k_gather1<<<dim3((n * 4 + B - 1) / B), dim3(B), 0, stream>>>(row_ptr, srcarr, dinv, h1, b1, W2, t, n);
    k_gather2<<<dim3((n * 8 + B - 1) / B), dim3(B), 0, stream>>>(row_ptr, srcarr, dinv, t, b2, out, n);
}